// Round 5
// baseline (214.291 us; speedup 1.0000x reference)
//
#include <hip/hip_runtime.h>
#include <math.h>

#define NFEAT 128
#define NHID  128
#define ALPHA 0.2f

typedef __attribute__((ext_vector_type(8))) short short8;
typedef __attribute__((ext_vector_type(4))) float f32x4;

__device__ inline unsigned int pack_bf16x2_rn(float x, float y) {
    unsigned int bx = __float_as_uint(x), by = __float_as_uint(y);
    bx += 0x7fffu + ((bx >> 16) & 1u);
    by += 0x7fffu + ((by >> 16) & 1u);
    return (bx >> 16) | (by & 0xffff0000u);
}

union Frag { unsigned int u[4]; uint4 v; short8 s; };

// ---------------------------------------------------------------------------
// One-time W transpose to bf16: Wt[n][k/2] packed dwords (32 KB in ws).
// 16 blocks, each does a 32x32 tile via LDS.
// ---------------------------------------------------------------------------
__global__ __launch_bounds__(256) void prep_wt_kernel(
    const float* __restrict__ W, unsigned int* __restrict__ Wtg)
{
    __shared__ float tile[32][33];
    const int t  = threadIdx.x;
    const int kt = blockIdx.x >> 2;       // k-tile (rows of W)
    const int nt = blockIdx.x & 3;        // n-tile (cols of W)

    // Coalesced read: r = t>>3 (32 rows), c = t&7 (8 float4 per row).
    {
        const int r = t >> 3, c = t & 7;
        const float4 v = *((const float4*)&W[(size_t)(kt * 32 + r) * NHID + nt * 32 + c * 4]);
        tile[r][c * 4 + 0] = v.x; tile[r][c * 4 + 1] = v.y;
        tile[r][c * 4 + 2] = v.z; tile[r][c * 4 + 3] = v.w;
    }
    __syncthreads();

    // Write transposed: Wt row n gets k-pairs. nn = t&31, kk = 2 per thread.
    const int nn = t & 31;
    #pragma unroll
    for (int i = 0; i < 2; ++i) {
        const int kk = (t >> 5) * 2 + i;  // 0..15 dword within tile
        Wtg[(size_t)(nt * 32 + nn) * 64 + kt * 16 + kk] =
            pack_bf16x2_rn(tile[kk * 2][nn], tile[kk * 2 + 1][nn]);
    }
}

// ---------------------------------------------------------------------------
// MFMA bf16 GEMM: h = x @ W (fp32) + hbu (bf16x2) + s1/s2 row dots.
// Wt-bf16 staged from global with coalesced uint4 loads into 68-stride LDS.
// ---------------------------------------------------------------------------
__global__ __launch_bounds__(256) void gemm_h_kernel(
    const float* __restrict__ x, const unsigned int* __restrict__ Wtg,
    const float* __restrict__ a, float* __restrict__ h,
    unsigned int* __restrict__ hbu,
    float* __restrict__ s1, float* __restrict__ s2, int n)
{
    __shared__ unsigned int Wtu[128 * 68];   // Wt[n][k] bf16 pairs, padded stride

    const int t = threadIdx.x;

    // Stage: 2048 uint4, 8 per thread, coalesced.
    #pragma unroll
    for (int i = 0; i < 8; ++i) {
        const int u  = i * 256 + t;
        const uint4 v = ((const uint4*)Wtg)[u];
        const int nn = u >> 4, kc = u & 15;
        *((uint4*)&Wtu[nn * 68 + kc * 4]) = v;
    }
    __syncthreads();

    const int w    = t >> 6;
    const int lane = t & 63;
    const int c    = lane & 15;
    const int quad = lane >> 4;

    const int rowbase = blockIdx.x * 128 + w * 32;

    float a1v[8], a2v[8];
    #pragma unroll
    for (int tt = 0; tt < 8; ++tt) {
        a1v[tt] = a[tt * 16 + c];
        a2v[tt] = a[NHID + tt * 16 + c];
    }

    f32x4 acc[2][8];
    #pragma unroll
    for (int rt = 0; rt < 2; ++rt)
        #pragma unroll
        for (int tt = 0; tt < 8; ++tt)
            acc[rt][tt] = (f32x4){0.f, 0.f, 0.f, 0.f};

    #pragma unroll
    for (int s = 0; s < 4; ++s) {
        Frag afr[2];
        #pragma unroll
        for (int rt = 0; rt < 2; ++rt) {
            int row = rowbase + rt * 16 + c;
            if (row >= n) row = n - 1;
            const float* xp = x + (size_t)row * NFEAT + s * 32 + quad * 8;
            const float4 xa = *((const float4*)xp);
            const float4 xb = *((const float4*)(xp + 4));
            afr[rt].u[0] = pack_bf16x2_rn(xa.x, xa.y);
            afr[rt].u[1] = pack_bf16x2_rn(xa.z, xa.w);
            afr[rt].u[2] = pack_bf16x2_rn(xb.x, xb.y);
            afr[rt].u[3] = pack_bf16x2_rn(xb.z, xb.w);
        }
        #pragma unroll
        for (int tt = 0; tt < 8; ++tt) {
            Frag bfr;
            bfr.v = *((const uint4*)&Wtu[(tt * 16 + c) * 68 + s * 16 + quad * 4]);
            acc[0][tt] = __builtin_amdgcn_mfma_f32_16x16x32_bf16(
                afr[0].s, bfr.s, acc[0][tt], 0, 0, 0);
            acc[1][tt] = __builtin_amdgcn_mfma_f32_16x16x32_bf16(
                afr[1].s, bfr.s, acc[1][tt], 0, 0, 0);
        }
    }

    #pragma unroll
    for (int rt = 0; rt < 2; ++rt) {
        #pragma unroll
        for (int r = 0; r < 4; ++r) {
            const int  row = rowbase + rt * 16 + quad * 4 + r;
            const bool ok  = (row < n);
            float p1 = 0.f, p2 = 0.f;
            #pragma unroll
            for (int tt = 0; tt < 8; ++tt) {
                const float v = acc[rt][tt][r];
                if (ok) h[(size_t)row * NHID + tt * 16 + c] = v;
                const float nb = __shfl_xor(v, 1, 64);
                if (ok && ((c & 1) == 0))
                    hbu[(size_t)row * 64 + tt * 8 + (c >> 1)] = pack_bf16x2_rn(v, nb);
                p1 = fmaf(v, a1v[tt], p1);
                p2 = fmaf(v, a2v[tt], p2);
            }
            #pragma unroll
            for (int off = 1; off <= 8; off <<= 1) {
                p1 += __shfl_xor(p1, off, 64);
                p2 += __shfl_xor(p2, off, 64);
            }
            if (ok && c == 0) { s1[row] = p1; s2[row] = p2; }
        }
    }
}

// ---------------------------------------------------------------------------
// Histogram: 4 edges/thread, fire-and-forget atomics.
// ---------------------------------------------------------------------------
__global__ __launch_bounds__(256) void hist_kernel(
    const int* __restrict__ ei, int* __restrict__ hist, int E)
{
    const int j0 = (blockIdx.x * 256 + threadIdx.x) * 4;
    if (j0 + 4 <= E) {
        const int4 s4 = *((const int4*)(ei + j0));
        atomicAdd(&hist[s4.x], 1);
        atomicAdd(&hist[s4.y], 1);
        atomicAdd(&hist[s4.z], 1);
        atomicAdd(&hist[s4.w], 1);
    } else {
        for (int j = j0; j < E; ++j) atomicAdd(&hist[ei[j]], 1);
    }
}

__global__ __launch_bounds__(256) void scan_block_kernel(
    const int* __restrict__ in, int* __restrict__ out, int* __restrict__ bsums, int n)
{
    __shared__ int s[256];
    const int tid = threadIdx.x;
    const int gid = blockIdx.x * 256 + tid;
    const int v = (gid < n) ? in[gid] : 0;
    s[tid] = v;
    __syncthreads();
    #pragma unroll
    for (int off = 1; off < 256; off <<= 1) {
        const int t2 = (tid >= off) ? s[tid - off] : 0;
        __syncthreads();
        s[tid] += t2;
        __syncthreads();
    }
    if (gid < n) out[gid] = s[tid] - v;
    if (tid == 255 && bsums) bsums[blockIdx.x] = s[255];
}

__global__ __launch_bounds__(256) void scan_add_kernel(
    int* __restrict__ row_ptr, int* __restrict__ cursor,
    const int* __restrict__ bsums_scan, int n, int E)
{
    const int gid = blockIdx.x * 256 + threadIdx.x;
    if (gid < n) {
        const int v = row_ptr[gid] + bsums_scan[gid >> 8];
        row_ptr[gid] = v;
        cursor[gid]  = v;
    }
    if (gid == 0) row_ptr[n] = E;
}

// ---------------------------------------------------------------------------
// Scatter: 4 edges/thread, 4 independent gather->atomic->store chains.
// ---------------------------------------------------------------------------
__global__ __launch_bounds__(256) void scatter_kernel(
    const int* __restrict__ ei, const float* __restrict__ s1,
    const float* __restrict__ s2, int* __restrict__ cursor,
    int2* __restrict__ epack, int E)
{
    const int j0 = (blockIdx.x * 256 + threadIdx.x) * 4;
    if (j0 + 4 <= E) {
        const int4 src4 = *((const int4*)(ei + j0));
        const int4 dst4 = *((const int4*)(ei + E + j0));
        const float sa = s1[src4.x], sb = s1[src4.y];
        const float sc = s1[src4.z], sd = s1[src4.w];
        const float ta = s2[dst4.x], tb = s2[dst4.y];
        const float tc = s2[dst4.z], td = s2[dst4.w];
        float v0 = sa + ta, v1 = sb + tb, v2 = sc + tc, v3 = sd + td;
        v0 = (v0 > 0.f) ? v0 : ALPHA * v0;  v0 = expf(-v0);
        v1 = (v1 > 0.f) ? v1 : ALPHA * v1;  v1 = expf(-v1);
        v2 = (v2 > 0.f) ? v2 : ALPHA * v2;  v2 = expf(-v2);
        v3 = (v3 > 0.f) ? v3 : ALPHA * v3;  v3 = expf(-v3);
        const int p0 = atomicAdd(&cursor[src4.x], 1);
        const int p1 = atomicAdd(&cursor[src4.y], 1);
        const int p2 = atomicAdd(&cursor[src4.z], 1);
        const int p3 = atomicAdd(&cursor[src4.w], 1);
        epack[p0] = make_int2(dst4.x, __float_as_int(v0));
        epack[p1] = make_int2(dst4.y, __float_as_int(v1));
        epack[p2] = make_int2(dst4.z, __float_as_int(v2));
        epack[p3] = make_int2(dst4.w, __float_as_int(v3));
    } else {
        for (int j = j0; j < E; ++j) {
            const int src = ei[j];
            const int dst = ei[E + j];
            float s = s1[src] + s2[dst];
            s = (s > 0.f) ? s : ALPHA * s;
            const float ev = expf(-s);
            const int pos = atomicAdd(&cursor[src], 1);
            epack[pos] = make_int2(dst, __float_as_int(ev));
        }
    }
}

// ---------------------------------------------------------------------------
// Aggregate + finalize: one wave per node, bf16 gathers, 8-deep unroll.
// ---------------------------------------------------------------------------
__global__ __launch_bounds__(256) void aggregate_kernel(
    const int* __restrict__ row_ptr, const int2* __restrict__ epack,
    const unsigned int* __restrict__ hbu, const float* __restrict__ h,
    float* __restrict__ out, int n)
{
    const int node = blockIdx.x * 4 + (threadIdx.x >> 6);
    const int lane = threadIdx.x & 63;
    if (node >= n) return;

    const int beg = row_ptr[node];
    const int end = row_ptr[node + 1];

    float acc0 = 0.f, acc1 = 0.f, rs = 0.f;

    int e = beg;
    for (; e + 8 <= end; e += 8) {
        int2 p[8];
        unsigned int u[8];
        #pragma unroll
        for (int i = 0; i < 8; ++i) p[i] = epack[e + i];
        #pragma unroll
        for (int i = 0; i < 8; ++i) u[i] = hbu[(size_t)p[i].x * 64 + lane];
        #pragma unroll
        for (int i = 0; i < 8; ++i) {
            const float ev = __int_as_float(p[i].y);
            acc0 = fmaf(ev, __uint_as_float(u[i] << 16), acc0);
            acc1 = fmaf(ev, __uint_as_float(u[i] & 0xffff0000u), acc1);
            rs += ev;
        }
    }
    for (; e + 2 <= end; e += 2) {
        const int2 p0 = epack[e], p1 = epack[e + 1];
        const unsigned int u0 = hbu[(size_t)p0.x * 64 + lane];
        const unsigned int u1 = hbu[(size_t)p1.x * 64 + lane];
        const float ev0 = __int_as_float(p0.y), ev1 = __int_as_float(p1.y);
        acc0 = fmaf(ev0, __uint_as_float(u0 << 16), acc0);
        acc1 = fmaf(ev0, __uint_as_float(u0 & 0xffff0000u), acc1);
        acc0 = fmaf(ev1, __uint_as_float(u1 << 16), acc0);
        acc1 = fmaf(ev1, __uint_as_float(u1 & 0xffff0000u), acc1);
        rs += ev0 + ev1;
    }
    if (e < end) {
        const int2 p0 = epack[e];
        const float ev0 = __int_as_float(p0.y);
        const unsigned int u0 = hbu[(size_t)p0.x * 64 + lane];
        acc0 = fmaf(ev0, __uint_as_float(u0 << 16), acc0);
        acc1 = fmaf(ev0, __uint_as_float(u0 & 0xffff0000u), acc1);
        rs += ev0;
    }

    const float rinv = 1.0f / (rs + 1e-16f);
    const float2 hv = ((const float2*)(h + (size_t)node * NHID))[lane];
    const float z0 = hv.x - acc0 * rinv;
    const float z1 = hv.y - acc1 * rinv;
    float2 o;
    o.x = (z0 > 0.f) ? z0 : (expf(z0) - 1.f);
    o.y = (z1 > 0.f) ? z1 : (expf(z1) - 1.f);
    ((float2*)(out + (size_t)node * NHID))[lane] = o;
}

// ---------------------------------------------------------------------------
extern "C" void kernel_launch(void* const* d_in, const int* in_sizes, int n_in,
                              void* d_out, int out_size, void* d_ws, size_t ws_size,
                              hipStream_t stream) {
    const float* x  = (const float*)d_in[0];
    const float* W  = (const float*)d_in[1];
    const float* a  = (const float*)d_in[2];
    const int*   ei = (const int*)d_in[3];

    const int n = in_sizes[0] / NFEAT;   // 50000
    const int E = in_sizes[3] / 2;       // 640000
    const int nb = (n + 255) / 256;

    float* out = (float*)d_out;

    // Workspace (4-byte units):
    //   h[n*128] | hbu[n*64] | s1[n] | s2[n] | epack[2E] | Wtg[8192] |
    //   hist[n] | bsums[256] | bsums_scan[256] | row_ptr[n+1] | cursor[n]
    float*        h     = (float*)d_ws;
    unsigned int* hbu   = (unsigned int*)(h + (size_t)n * NHID);
    float*        s1    = (float*)(hbu + (size_t)n * 64);
    float*        s2    = s1 + n;
    int2*         epack = (int2*)(s2 + n);
    unsigned int* Wtg   = (unsigned int*)(epack + E);
    int*          hist  = (int*)(Wtg + 8192);
    int*          bsums = hist + n;
    int*          bsums_scan = bsums + 256;
    int*          row_ptr    = bsums_scan + 256;
    int*          cursor     = row_ptr + (n + 1);

    hipMemsetAsync(hist, 0, ((size_t)n + 256) * sizeof(int), stream);

    prep_wt_kernel<<<16, 256, 0, stream>>>(W, Wtg);

    gemm_h_kernel<<<(n + 127) / 128, 256, 0, stream>>>(x, Wtg, a, h, hbu, s1, s2, n);

    hist_kernel<<<(E / 4 + 255) / 256, 256, 0, stream>>>(ei, hist, E);

    scan_block_kernel<<<nb, 256, 0, stream>>>(hist, row_ptr, bsums, n);
    scan_block_kernel<<<1, 256, 0, stream>>>(bsums, bsums_scan, nullptr, 256);
    scan_add_kernel<<<nb, 256, 0, stream>>>(row_ptr, cursor, bsums_scan, n, E);

    scatter_kernel<<<(E / 4 + 255) / 256, 256, 0, stream>>>(ei, s1, s2, cursor, epack, E);

    aggregate_kernel<<<(n + 3) / 4, 256, 0, stream>>>(row_ptr, epack, hbu, h, out, n);
}

// Round 6
// 195.616 us; speedup vs baseline: 1.0955x; 1.0955x over previous
//
#include <hip/hip_runtime.h>
#include <hip/hip_fp16.h>
#include <math.h>

#define NFEAT 128
#define NHID  128
#define ALPHA 0.2f

typedef __attribute__((ext_vector_type(8))) short short8;
typedef __attribute__((ext_vector_type(4))) float f32x4;

__device__ inline unsigned int pack_bf16x2_rn(float x, float y) {
    unsigned int bx = __float_as_uint(x), by = __float_as_uint(y);
    bx += 0x7fffu + ((bx >> 16) & 1u);
    by += 0x7fffu + ((by >> 16) & 1u);
    return (bx >> 16) | (by & 0xffff0000u);
}

union Frag { unsigned int u[4]; uint4 v; short8 s; };

// ---------------------------------------------------------------------------
// One-time W transpose to bf16: Wt[n][k/2] packed dwords (32 KB in ws).
// ---------------------------------------------------------------------------
__global__ __launch_bounds__(256) void prep_wt_kernel(
    const float* __restrict__ W, unsigned int* __restrict__ Wtg)
{
    __shared__ float tile[32][33];
    const int t  = threadIdx.x;
    const int kt = blockIdx.x >> 2;
    const int nt = blockIdx.x & 3;

    {
        const int r = t >> 3, c = t & 7;
        const float4 v = *((const float4*)&W[(size_t)(kt * 32 + r) * NHID + nt * 32 + c * 4]);
        tile[r][c * 4 + 0] = v.x; tile[r][c * 4 + 1] = v.y;
        tile[r][c * 4 + 2] = v.z; tile[r][c * 4 + 3] = v.w;
    }
    __syncthreads();

    const int nn = t & 31;
    #pragma unroll
    for (int i = 0; i < 2; ++i) {
        const int kk = (t >> 5) * 2 + i;
        Wtg[(size_t)(nt * 32 + nn) * 64 + kt * 16 + kk] =
            pack_bf16x2_rn(tile[kk * 2][nn], tile[kk * 2 + 1][nn]);
    }
}

// ---------------------------------------------------------------------------
// MFMA bf16 GEMM: h = x @ W (fp32) + hbu (bf16x2) + s1/s2 row dots.
// ---------------------------------------------------------------------------
__global__ __launch_bounds__(256) void gemm_h_kernel(
    const float* __restrict__ x, const unsigned int* __restrict__ Wtg,
    const float* __restrict__ a, float* __restrict__ h,
    unsigned int* __restrict__ hbu,
    float* __restrict__ s1, float* __restrict__ s2, int n)
{
    __shared__ unsigned int Wtu[128 * 68];

    const int t = threadIdx.x;

    #pragma unroll
    for (int i = 0; i < 8; ++i) {
        const int u  = i * 256 + t;
        const uint4 v = ((const uint4*)Wtg)[u];
        const int nn = u >> 4, kc = u & 15;
        *((uint4*)&Wtu[nn * 68 + kc * 4]) = v;
    }
    __syncthreads();

    const int w    = t >> 6;
    const int lane = t & 63;
    const int c    = lane & 15;
    const int quad = lane >> 4;

    const int rowbase = blockIdx.x * 128 + w * 32;

    float a1v[8], a2v[8];
    #pragma unroll
    for (int tt = 0; tt < 8; ++tt) {
        a1v[tt] = a[tt * 16 + c];
        a2v[tt] = a[NHID + tt * 16 + c];
    }

    f32x4 acc[2][8];
    #pragma unroll
    for (int rt = 0; rt < 2; ++rt)
        #pragma unroll
        for (int tt = 0; tt < 8; ++tt)
            acc[rt][tt] = (f32x4){0.f, 0.f, 0.f, 0.f};

    #pragma unroll
    for (int s = 0; s < 4; ++s) {
        Frag afr[2];
        #pragma unroll
        for (int rt = 0; rt < 2; ++rt) {
            int row = rowbase + rt * 16 + c;
            if (row >= n) row = n - 1;
            const float* xp = x + (size_t)row * NFEAT + s * 32 + quad * 8;
            const float4 xa = *((const float4*)xp);
            const float4 xb = *((const float4*)(xp + 4));
            afr[rt].u[0] = pack_bf16x2_rn(xa.x, xa.y);
            afr[rt].u[1] = pack_bf16x2_rn(xa.z, xa.w);
            afr[rt].u[2] = pack_bf16x2_rn(xb.x, xb.y);
            afr[rt].u[3] = pack_bf16x2_rn(xb.z, xb.w);
        }
        #pragma unroll
        for (int tt = 0; tt < 8; ++tt) {
            Frag bfr;
            bfr.v = *((const uint4*)&Wtu[(tt * 16 + c) * 68 + s * 16 + quad * 4]);
            acc[0][tt] = __builtin_amdgcn_mfma_f32_16x16x32_bf16(
                afr[0].s, bfr.s, acc[0][tt], 0, 0, 0);
            acc[1][tt] = __builtin_amdgcn_mfma_f32_16x16x32_bf16(
                afr[1].s, bfr.s, acc[1][tt], 0, 0, 0);
        }
    }

    #pragma unroll
    for (int rt = 0; rt < 2; ++rt) {
        #pragma unroll
        for (int r = 0; r < 4; ++r) {
            const int  row = rowbase + rt * 16 + quad * 4 + r;
            const bool ok  = (row < n);
            float p1 = 0.f, p2 = 0.f;
            #pragma unroll
            for (int tt = 0; tt < 8; ++tt) {
                const float v = acc[rt][tt][r];
                if (ok) h[(size_t)row * NHID + tt * 16 + c] = v;
                const float nb = __shfl_xor(v, 1, 64);
                if (ok && ((c & 1) == 0))
                    hbu[(size_t)row * 64 + tt * 8 + (c >> 1)] = pack_bf16x2_rn(v, nb);
                p1 = fmaf(v, a1v[tt], p1);
                p2 = fmaf(v, a2v[tt], p2);
            }
            #pragma unroll
            for (int off = 1; off <= 8; off <<= 1) {
                p1 += __shfl_xor(p1, off, 64);
                p2 += __shfl_xor(p2, off, 64);
            }
            if (ok && c == 0) { s1[row] = p1; s2[row] = p2; }
        }
    }
}

// ---------------------------------------------------------------------------
// Histogram: 4 edges/thread, fire-and-forget atomics.
// ---------------------------------------------------------------------------
__global__ __launch_bounds__(256) void hist_kernel(
    const int* __restrict__ ei, int* __restrict__ hist, int E)
{
    const int j0 = (blockIdx.x * 256 + threadIdx.x) * 4;
    if (j0 + 4 <= E) {
        const int4 s4 = *((const int4*)(ei + j0));
        atomicAdd(&hist[s4.x], 1);
        atomicAdd(&hist[s4.y], 1);
        atomicAdd(&hist[s4.z], 1);
        atomicAdd(&hist[s4.w], 1);
    } else {
        for (int j = j0; j < E; ++j) atomicAdd(&hist[ei[j]], 1);
    }
}

__global__ __launch_bounds__(256) void scan_block_kernel(
    const int* __restrict__ in, int* __restrict__ out, int* __restrict__ bsums, int n)
{
    __shared__ int s[256];
    const int tid = threadIdx.x;
    const int gid = blockIdx.x * 256 + tid;
    const int v = (gid < n) ? in[gid] : 0;
    s[tid] = v;
    __syncthreads();
    #pragma unroll
    for (int off = 1; off < 256; off <<= 1) {
        const int t2 = (tid >= off) ? s[tid - off] : 0;
        __syncthreads();
        s[tid] += t2;
        __syncthreads();
    }
    if (gid < n) out[gid] = s[tid] - v;
    if (tid == 255 && bsums) bsums[blockIdx.x] = s[255];
}

__global__ __launch_bounds__(256) void scan_add_kernel(
    int* __restrict__ row_ptr, int* __restrict__ cursor,
    const int* __restrict__ bsums_scan, int n, int E)
{
    const int gid = blockIdx.x * 256 + threadIdx.x;
    if (gid < n) {
        const int v = row_ptr[gid] + bsums_scan[gid >> 8];
        row_ptr[gid] = v;
        cursor[gid]  = v;
    }
    if (gid == 0) row_ptr[n] = E;
}

// ---------------------------------------------------------------------------
// Scatter: 1 edge/thread, 4-byte records (dst<<16 | fp16(ev)).
// ---------------------------------------------------------------------------
__global__ __launch_bounds__(256) void scatter_kernel(
    const int* __restrict__ ei, const float* __restrict__ s1,
    const float* __restrict__ s2, int* __restrict__ cursor,
    unsigned int* __restrict__ erec, int E)
{
    const int j = blockIdx.x * 256 + threadIdx.x;
    if (j >= E) return;
    const int src = ei[j];
    const int dst = ei[E + j];
    float s = s1[src] + s2[dst];
    s = (s > 0.f) ? s : ALPHA * s;
    const float ev = expf(-s);
    const unsigned int evh = (unsigned int)__half_as_ushort(__float2half(ev));
    const int pos = atomicAdd(&cursor[src], 1);
    erec[pos] = ((unsigned int)dst << 16) | evh;
}

// ---------------------------------------------------------------------------
// Aggregate + finalize: 16-lane group per node (4 nodes/wave).
// Lane handles 8 features: one uint4 (16 B) bf16 gather per edge.
// ---------------------------------------------------------------------------
__global__ __launch_bounds__(256) void aggregate_kernel(
    const int* __restrict__ row_ptr, const unsigned int* __restrict__ erec,
    const unsigned int* __restrict__ hbu, const float* __restrict__ h,
    float* __restrict__ out, int n)
{
    const int node = blockIdx.x * 16 + (threadIdx.x >> 4);
    const int l    = threadIdx.x & 15;
    if (node >= n) return;

    const int beg = row_ptr[node];
    const int end = row_ptr[node + 1];

    float acc[8];
    #pragma unroll
    for (int i = 0; i < 8; ++i) acc[i] = 0.f;
    float rs = 0.f;

    int e = beg;
    for (; e + 4 <= end; e += 4) {
        unsigned int r0 = erec[e],     r1 = erec[e + 1];
        unsigned int r2 = erec[e + 2], r3 = erec[e + 3];
        const uint4 u0 = ((const uint4*)(hbu + (size_t)(r0 >> 16) * 64))[l];
        const uint4 u1 = ((const uint4*)(hbu + (size_t)(r1 >> 16) * 64))[l];
        const uint4 u2 = ((const uint4*)(hbu + (size_t)(r2 >> 16) * 64))[l];
        const uint4 u3 = ((const uint4*)(hbu + (size_t)(r3 >> 16) * 64))[l];
        const float e0 = __half2float(__ushort_as_half((unsigned short)(r0 & 0xffffu)));
        const float e1 = __half2float(__ushort_as_half((unsigned short)(r1 & 0xffffu)));
        const float e2 = __half2float(__ushort_as_half((unsigned short)(r2 & 0xffffu)));
        const float e3 = __half2float(__ushort_as_half((unsigned short)(r3 & 0xffffu)));
        #define ACC4(u, ev)                                                   \
            acc[0] = fmaf(ev, __uint_as_float(u.x << 16), acc[0]);            \
            acc[1] = fmaf(ev, __uint_as_float(u.x & 0xffff0000u), acc[1]);    \
            acc[2] = fmaf(ev, __uint_as_float(u.y << 16), acc[2]);            \
            acc[3] = fmaf(ev, __uint_as_float(u.y & 0xffff0000u), acc[3]);    \
            acc[4] = fmaf(ev, __uint_as_float(u.z << 16), acc[4]);            \
            acc[5] = fmaf(ev, __uint_as_float(u.z & 0xffff0000u), acc[5]);    \
            acc[6] = fmaf(ev, __uint_as_float(u.w << 16), acc[6]);            \
            acc[7] = fmaf(ev, __uint_as_float(u.w & 0xffff0000u), acc[7]);
        ACC4(u0, e0); ACC4(u1, e1); ACC4(u2, e2); ACC4(u3, e3);
        rs += (e0 + e1) + (e2 + e3);
    }
    for (; e < end; ++e) {
        const unsigned int r0 = erec[e];
        const uint4 u0 = ((const uint4*)(hbu + (size_t)(r0 >> 16) * 64))[l];
        const float e0 = __half2float(__ushort_as_half((unsigned short)(r0 & 0xffffu)));
        ACC4(u0, e0);
        rs += e0;
    }
    #undef ACC4

    const float rinv = 1.0f / (rs + 1e-16f);
    const float4* hp = (const float4*)(h + (size_t)node * NHID);
    const float4 ha = hp[l * 2], hb = hp[l * 2 + 1];
    float4 oa, ob;
    float z;
    z = ha.x - acc[0] * rinv; oa.x = (z > 0.f) ? z : (expf(z) - 1.f);
    z = ha.y - acc[1] * rinv; oa.y = (z > 0.f) ? z : (expf(z) - 1.f);
    z = ha.z - acc[2] * rinv; oa.z = (z > 0.f) ? z : (expf(z) - 1.f);
    z = ha.w - acc[3] * rinv; oa.w = (z > 0.f) ? z : (expf(z) - 1.f);
    z = hb.x - acc[4] * rinv; ob.x = (z > 0.f) ? z : (expf(z) - 1.f);
    z = hb.y - acc[5] * rinv; ob.y = (z > 0.f) ? z : (expf(z) - 1.f);
    z = hb.z - acc[6] * rinv; ob.z = (z > 0.f) ? z : (expf(z) - 1.f);
    z = hb.w - acc[7] * rinv; ob.w = (z > 0.f) ? z : (expf(z) - 1.f);
    float4* op = (float4*)(out + (size_t)node * NHID);
    op[l * 2]     = oa;
    op[l * 2 + 1] = ob;
}

// ---------------------------------------------------------------------------
extern "C" void kernel_launch(void* const* d_in, const int* in_sizes, int n_in,
                              void* d_out, int out_size, void* d_ws, size_t ws_size,
                              hipStream_t stream) {
    const float* x  = (const float*)d_in[0];
    const float* W  = (const float*)d_in[1];
    const float* a  = (const float*)d_in[2];
    const int*   ei = (const int*)d_in[3];

    const int n = in_sizes[0] / NFEAT;   // 50000
    const int E = in_sizes[3] / 2;       // 640000
    const int nb = (n + 255) / 256;

    float* out = (float*)d_out;

    // Workspace (4-byte units):
    //   h[n*128] | hbu[n*64] | s1[n] | s2[n] | erec[E] | Wtg[8192] |
    //   hist[n] | bsums[256] | bsums_scan[256] | row_ptr[n+1] | cursor[n]
    float*        h     = (float*)d_ws;
    unsigned int* hbu   = (unsigned int*)(h + (size_t)n * NHID);
    float*        s1    = (float*)(hbu + (size_t)n * 64);
    float*        s2    = s1 + n;
    unsigned int* erec  = (unsigned int*)(s2 + n);
    unsigned int* Wtg   = erec + E;
    int*          hist  = (int*)(Wtg + 8192);
    int*          bsums = hist + n;
    int*          bsums_scan = bsums + 256;
    int*          row_ptr    = bsums_scan + 256;
    int*          cursor     = row_ptr + (n + 1);

    hipMemsetAsync(hist, 0, ((size_t)n + 256) * sizeof(int), stream);

    prep_wt_kernel<<<16, 256, 0, stream>>>(W, Wtg);

    gemm_h_kernel<<<(n + 127) / 128, 256, 0, stream>>>(x, Wtg, a, h, hbu, s1, s2, n);

    hist_kernel<<<(E / 4 + 255) / 256, 256, 0, stream>>>(ei, hist, E);

    scan_block_kernel<<<nb, 256, 0, stream>>>(hist, row_ptr, bsums, n);
    scan_block_kernel<<<1, 256, 0, stream>>>(bsums, bsums_scan, nullptr, 256);
    scan_add_kernel<<<nb, 256, 0, stream>>>(row_ptr, cursor, bsums_scan, n, E);

    scatter_kernel<<<(E + 255) / 256, 256, 0, stream>>>(ei, s1, s2, cursor, erec, E);

    aggregate_kernel<<<(n + 15) / 16, 256, 0, stream>>>(row_ptr, erec, hbu, h, out, n);
}

// Round 7
// 191.848 us; speedup vs baseline: 1.1170x; 1.0196x over previous
//
#include <hip/hip_runtime.h>
#include <hip/hip_fp16.h>
#include <math.h>

#define NFEAT 128
#define NHID  128
#define ALPHA 0.2f

typedef __attribute__((ext_vector_type(8))) short short8;
typedef __attribute__((ext_vector_type(4))) float f32x4;

__device__ inline unsigned int pack_bf16x2_rn(float x, float y) {
    unsigned int bx = __float_as_uint(x), by = __float_as_uint(y);
    bx += 0x7fffu + ((bx >> 16) & 1u);
    by += 0x7fffu + ((by >> 16) & 1u);
    return (bx >> 16) | (by & 0xffff0000u);
}

union Frag { unsigned int u[4]; uint4 v; short8 s; };

// ---------------------------------------------------------------------------
// One-time W transpose to bf16: Wt[n][k/2] packed dwords (32 KB in ws).
// ---------------------------------------------------------------------------
__global__ __launch_bounds__(256) void prep_wt_kernel(
    const float* __restrict__ W, unsigned int* __restrict__ Wtg)
{
    __shared__ float tile[32][33];
    const int t  = threadIdx.x;
    const int kt = blockIdx.x >> 2;
    const int nt = blockIdx.x & 3;

    {
        const int r = t >> 3, c = t & 7;
        const float4 v = *((const float4*)&W[(size_t)(kt * 32 + r) * NHID + nt * 32 + c * 4]);
        tile[r][c * 4 + 0] = v.x; tile[r][c * 4 + 1] = v.y;
        tile[r][c * 4 + 2] = v.z; tile[r][c * 4 + 3] = v.w;
    }
    __syncthreads();

    const int nn = t & 31;
    #pragma unroll
    for (int i = 0; i < 2; ++i) {
        const int kk = (t >> 5) * 2 + i;
        Wtg[(size_t)(nt * 32 + nn) * 64 + kt * 16 + kk] =
            pack_bf16x2_rn(tile[kk * 2][nn], tile[kk * 2 + 1][nn]);
    }
}

// ---------------------------------------------------------------------------
// MFMA bf16 GEMM + fused edge histogram.
// h = x @ W (fp32) + hbu (bf16 pairs, [p][c] layout: hbu[row*64 + p*16 + c] =
// pack(col 32p+c, col 32p+16+c)) + s1/s2 row dots.
// Hist atomics are fire-and-forget; they hide under MFMA + staging.
// ---------------------------------------------------------------------------
__global__ __launch_bounds__(256) void gemm_h_kernel(
    const float* __restrict__ x, const unsigned int* __restrict__ Wtg,
    const float* __restrict__ a, float* __restrict__ h,
    unsigned int* __restrict__ hbu,
    float* __restrict__ s1, float* __restrict__ s2, int n,
    const int* __restrict__ ei, int* __restrict__ hist, int E)
{
    __shared__ unsigned int Wtu[128 * 68];

    const int t = threadIdx.x;

    // Stage Wt: 2048 uint4, 8 per thread, coalesced.
    #pragma unroll
    for (int i = 0; i < 8; ++i) {
        const int u  = i * 256 + t;
        const uint4 v = ((const uint4*)Wtg)[u];
        const int nn = u >> 4, kc = u & 15;
        *((uint4*)&Wtu[nn * 68 + kc * 4]) = v;
    }

    // Fused histogram chunk (independent of GEMM data).
    {
        const int E4   = E >> 2;
        const int nthr = gridDim.x << 8;
        const int g    = blockIdx.x * 256 + t;
        for (int idx = g; idx < E4; idx += nthr) {
            const int4 s4 = ((const int4*)ei)[idx];
            atomicAdd(&hist[s4.x], 1);
            atomicAdd(&hist[s4.y], 1);
            atomicAdd(&hist[s4.z], 1);
            atomicAdd(&hist[s4.w], 1);
        }
        for (int j = (E4 << 2) + g; j < E; j += nthr) atomicAdd(&hist[ei[j]], 1);
    }
    __syncthreads();

    const int w    = t >> 6;
    const int lane = t & 63;
    const int c    = lane & 15;
    const int quad = lane >> 4;

    const int rowbase = blockIdx.x * 128 + w * 32;

    float a1v[8], a2v[8];
    #pragma unroll
    for (int tt = 0; tt < 8; ++tt) {
        a1v[tt] = a[tt * 16 + c];
        a2v[tt] = a[NHID + tt * 16 + c];
    }

    f32x4 acc[2][8];
    #pragma unroll
    for (int rt = 0; rt < 2; ++rt)
        #pragma unroll
        for (int tt = 0; tt < 8; ++tt)
            acc[rt][tt] = (f32x4){0.f, 0.f, 0.f, 0.f};

    #pragma unroll
    for (int s = 0; s < 4; ++s) {
        Frag afr[2];
        #pragma unroll
        for (int rt = 0; rt < 2; ++rt) {
            int row = rowbase + rt * 16 + c;
            if (row >= n) row = n - 1;
            const float* xp = x + (size_t)row * NFEAT + s * 32 + quad * 8;
            const float4 xa = *((const float4*)xp);
            const float4 xb = *((const float4*)(xp + 4));
            afr[rt].u[0] = pack_bf16x2_rn(xa.x, xa.y);
            afr[rt].u[1] = pack_bf16x2_rn(xa.z, xa.w);
            afr[rt].u[2] = pack_bf16x2_rn(xb.x, xb.y);
            afr[rt].u[3] = pack_bf16x2_rn(xb.z, xb.w);
        }
        #pragma unroll
        for (int tt = 0; tt < 8; ++tt) {
            Frag bfr;
            bfr.v = *((const uint4*)&Wtu[(tt * 16 + c) * 68 + s * 16 + quad * 4]);
            acc[0][tt] = __builtin_amdgcn_mfma_f32_16x16x32_bf16(
                afr[0].s, bfr.s, acc[0][tt], 0, 0, 0);
            acc[1][tt] = __builtin_amdgcn_mfma_f32_16x16x32_bf16(
                afr[1].s, bfr.s, acc[1][tt], 0, 0, 0);
        }
    }

    // Epilogue: no shuffles except the s1/s2 16-lane reduction.
    #pragma unroll
    for (int rt = 0; rt < 2; ++rt) {
        #pragma unroll
        for (int r = 0; r < 4; ++r) {
            const int  row = rowbase + rt * 16 + quad * 4 + r;
            const bool ok  = (row < n);
            float p1 = 0.f, p2 = 0.f;
            #pragma unroll
            for (int tt = 0; tt < 8; ++tt) {
                const float v = acc[rt][tt][r];
                if (ok) h[(size_t)row * NHID + tt * 16 + c] = v;
                p1 = fmaf(v, a1v[tt], p1);
                p2 = fmaf(v, a2v[tt], p2);
            }
            #pragma unroll
            for (int p = 0; p < 4; ++p) {
                if (ok) hbu[(size_t)row * 64 + p * 16 + c] =
                    pack_bf16x2_rn(acc[rt][2 * p][r], acc[rt][2 * p + 1][r]);
            }
            #pragma unroll
            for (int off = 1; off <= 8; off <<= 1) {
                p1 += __shfl_xor(p1, off, 64);
                p2 += __shfl_xor(p2, off, 64);
            }
            if (ok && c == 0) { s1[row] = p1; s2[row] = p2; }
        }
    }
}

__global__ __launch_bounds__(256) void scan_block_kernel(
    const int* __restrict__ in, int* __restrict__ out, int* __restrict__ bsums, int n)
{
    __shared__ int s[256];
    const int tid = threadIdx.x;
    const int gid = blockIdx.x * 256 + tid;
    const int v = (gid < n) ? in[gid] : 0;
    s[tid] = v;
    __syncthreads();
    #pragma unroll
    for (int off = 1; off < 256; off <<= 1) {
        const int t2 = (tid >= off) ? s[tid - off] : 0;
        __syncthreads();
        s[tid] += t2;
        __syncthreads();
    }
    if (gid < n) out[gid] = s[tid] - v;
    if (tid == 255 && bsums) bsums[blockIdx.x] = s[255];
}

__global__ __launch_bounds__(256) void scan_add_kernel(
    int* __restrict__ row_ptr, int* __restrict__ cursor,
    const int* __restrict__ bsums_scan, int n, int E)
{
    const int gid = blockIdx.x * 256 + threadIdx.x;
    if (gid < n) {
        const int v = row_ptr[gid] + bsums_scan[gid >> 8];
        row_ptr[gid] = v;
        cursor[gid]  = v;
    }
    if (gid == 0) row_ptr[n] = E;
}

// ---------------------------------------------------------------------------
// Scatter: 1 edge/thread, 4-byte records (dst<<16 | fp16(ev)).
// ---------------------------------------------------------------------------
__global__ __launch_bounds__(256) void scatter_kernel(
    const int* __restrict__ ei, const float* __restrict__ s1,
    const float* __restrict__ s2, int* __restrict__ cursor,
    unsigned int* __restrict__ erec, int E)
{
    const int j = blockIdx.x * 256 + threadIdx.x;
    if (j >= E) return;
    const int src = ei[j];
    const int dst = ei[E + j];
    float s = s1[src] + s2[dst];
    s = (s > 0.f) ? s : ALPHA * s;
    const float ev = expf(-s);
    const unsigned int evh = (unsigned int)__half_as_ushort(__float2half(ev));
    const int pos = atomicAdd(&cursor[src], 1);
    erec[pos] = ((unsigned int)dst << 16) | evh;
}

// ---------------------------------------------------------------------------
// Aggregate + finalize: 16-lane group per node (4 nodes/wave), 8-deep unroll.
// hbu layout: dword (p*16+c) of a row = pack(col 32p+c, col 32p+16+c).
// Lane l reads uint4 at dwords l*4..l*4+3 -> p=l>>2, c=4*(l&3)+d:
//   acc[d]   <- col 32p+4q+d      (q=l&3)
//   acc[4+d] <- col 32p+16+4q+d
// ---------------------------------------------------------------------------
__global__ __launch_bounds__(256) void aggregate_kernel(
    const int* __restrict__ row_ptr, const unsigned int* __restrict__ erec,
    const unsigned int* __restrict__ hbu, const float* __restrict__ h,
    float* __restrict__ out, int n)
{
    const int node = blockIdx.x * 16 + (threadIdx.x >> 4);
    const int l    = threadIdx.x & 15;
    if (node >= n) return;

    const int beg = row_ptr[node];
    const int end = row_ptr[node + 1];

    float acc[8];
    #pragma unroll
    for (int i = 0; i < 8; ++i) acc[i] = 0.f;
    float rs = 0.f;

    #define BL(x) __uint_as_float((x) << 16)
    #define BH(x) __uint_as_float((x) & 0xffff0000u)
    #define ACC4(u, ev)                                   \
        acc[0] = fmaf(ev, BL(u.x), acc[0]);               \
        acc[4] = fmaf(ev, BH(u.x), acc[4]);               \
        acc[1] = fmaf(ev, BL(u.y), acc[1]);               \
        acc[5] = fmaf(ev, BH(u.y), acc[5]);               \
        acc[2] = fmaf(ev, BL(u.z), acc[2]);               \
        acc[6] = fmaf(ev, BH(u.z), acc[6]);               \
        acc[3] = fmaf(ev, BL(u.w), acc[3]);               \
        acc[7] = fmaf(ev, BH(u.w), acc[7]);

    int e = beg;
    for (; e + 8 <= end; e += 8) {
        unsigned int rr[8];
        uint4 u[8];
        #pragma unroll
        for (int i = 0; i < 8; ++i) rr[i] = erec[e + i];
        #pragma unroll
        for (int i = 0; i < 8; ++i)
            u[i] = ((const uint4*)(hbu + (size_t)(rr[i] >> 16) * 64))[l];
        #pragma unroll
        for (int i = 0; i < 8; ++i) {
            const float ev = __half2float(__ushort_as_half((unsigned short)(rr[i] & 0xffffu)));
            ACC4(u[i], ev);
            rs += ev;
        }
    }
    for (; e + 2 <= end; e += 2) {
        const unsigned int r0 = erec[e], r1 = erec[e + 1];
        const uint4 u0 = ((const uint4*)(hbu + (size_t)(r0 >> 16) * 64))[l];
        const uint4 u1 = ((const uint4*)(hbu + (size_t)(r1 >> 16) * 64))[l];
        const float e0 = __half2float(__ushort_as_half((unsigned short)(r0 & 0xffffu)));
        const float e1 = __half2float(__ushort_as_half((unsigned short)(r1 & 0xffffu)));
        ACC4(u0, e0); ACC4(u1, e1);
        rs += e0 + e1;
    }
    if (e < end) {
        const unsigned int r0 = erec[e];
        const uint4 u0 = ((const uint4*)(hbu + (size_t)(r0 >> 16) * 64))[l];
        const float e0 = __half2float(__ushort_as_half((unsigned short)(r0 & 0xffffu)));
        ACC4(u0, e0);
        rs += e0;
    }
    #undef ACC4
    #undef BL
    #undef BH

    const float rinv = 1.0f / (rs + 1e-16f);
    const int p = l >> 2, q = l & 3;
    const float4* hp4 = (const float4*)(h + (size_t)node * NHID);
    const float4 ha = hp4[8 * p + q];
    const float4 hb = hp4[8 * p + 4 + q];
    float4 oa, ob;
    float z;
    z = ha.x - acc[0] * rinv; oa.x = (z > 0.f) ? z : (expf(z) - 1.f);
    z = ha.y - acc[1] * rinv; oa.y = (z > 0.f) ? z : (expf(z) - 1.f);
    z = ha.z - acc[2] * rinv; oa.z = (z > 0.f) ? z : (expf(z) - 1.f);
    z = ha.w - acc[3] * rinv; oa.w = (z > 0.f) ? z : (expf(z) - 1.f);
    z = hb.x - acc[4] * rinv; ob.x = (z > 0.f) ? z : (expf(z) - 1.f);
    z = hb.y - acc[5] * rinv; ob.y = (z > 0.f) ? z : (expf(z) - 1.f);
    z = hb.z - acc[6] * rinv; ob.z = (z > 0.f) ? z : (expf(z) - 1.f);
    z = hb.w - acc[7] * rinv; ob.w = (z > 0.f) ? z : (expf(z) - 1.f);
    float4* op = (float4*)(out + (size_t)node * NHID);
    op[8 * p + q]     = oa;
    op[8 * p + 4 + q] = ob;
}

// ---------------------------------------------------------------------------
extern "C" void kernel_launch(void* const* d_in, const int* in_sizes, int n_in,
                              void* d_out, int out_size, void* d_ws, size_t ws_size,
                              hipStream_t stream) {
    const float* x  = (const float*)d_in[0];
    const float* W  = (const float*)d_in[1];
    const float* a  = (const float*)d_in[2];
    const int*   ei = (const int*)d_in[3];

    const int n = in_sizes[0] / NFEAT;   // 50000
    const int E = in_sizes[3] / 2;       // 640000
    const int nb = (n + 255) / 256;

    float* out = (float*)d_out;

    // Workspace (4-byte units):
    //   h[n*128] | hbu[n*64] | s1[n] | s2[n] | erec[E] | Wtg[8192] |
    //   hist[n] | bsums[256] | bsums_scan[256] | row_ptr[n+1] | cursor[n]
    float*        h     = (float*)d_ws;
    unsigned int* hbu   = (unsigned int*)(h + (size_t)n * NHID);
    float*        s1    = (float*)(hbu + (size_t)n * 64);
    float*        s2    = s1 + n;
    unsigned int* erec  = (unsigned int*)(s2 + n);
    unsigned int* Wtg   = erec + E;
    int*          hist  = (int*)(Wtg + 8192);
    int*          bsums = hist + n;
    int*          bsums_scan = bsums + 256;
    int*          row_ptr    = bsums_scan + 256;
    int*          cursor     = row_ptr + (n + 1);

    hipMemsetAsync(hist, 0, ((size_t)n + 256) * sizeof(int), stream);

    prep_wt_kernel<<<16, 256, 0, stream>>>(W, Wtg);

    gemm_h_kernel<<<(n + 127) / 128, 256, 0, stream>>>(x, Wtg, a, h, hbu, s1, s2, n,
                                                       ei, hist, E);

    scan_block_kernel<<<nb, 256, 0, stream>>>(hist, row_ptr, bsums, n);
    scan_block_kernel<<<1, 256, 0, stream>>>(bsums, bsums_scan, nullptr, 256);
    scan_add_kernel<<<nb, 256, 0, stream>>>(row_ptr, cursor, bsums_scan, n, E);

    scatter_kernel<<<(E + 255) / 256, 256, 0, stream>>>(ei, s1, s2, cursor, erec, E);

    aggregate_kernel<<<(n + 15) / 16, 256, 0, stream>>>(row_ptr, erec, hbu, h, out, n);
}

// Round 8
// 180.578 us; speedup vs baseline: 1.1867x; 1.0624x over previous
//
#include <hip/hip_runtime.h>
#include <hip/hip_fp16.h>
#include <math.h>

#define NFEAT 128
#define NHID  128
#define ALPHA 0.2f

typedef __attribute__((ext_vector_type(8))) short short8;
typedef __attribute__((ext_vector_type(4))) float f32x4;

__device__ inline unsigned int pack_bf16x2_rn(float x, float y) {
    unsigned int bx = __float_as_uint(x), by = __float_as_uint(y);
    bx += 0x7fffu + ((bx >> 16) & 1u);
    by += 0x7fffu + ((by >> 16) & 1u);
    return (bx >> 16) | (by & 0xffff0000u);
}

union Frag { unsigned int u[4]; uint4 v; short8 s; };

// ---------------------------------------------------------------------------
// One-time W transpose to bf16: Wt[n][k/2] packed dwords (32 KB in ws).
// ---------------------------------------------------------------------------
__global__ __launch_bounds__(256) void prep_wt_kernel(
    const float* __restrict__ W, unsigned int* __restrict__ Wtg)
{
    __shared__ float tile[32][33];
    const int t  = threadIdx.x;
    const int kt = blockIdx.x >> 2;
    const int nt = blockIdx.x & 3;

    {
        const int r = t >> 3, c = t & 7;
        const float4 v = *((const float4*)&W[(size_t)(kt * 32 + r) * NHID + nt * 32 + c * 4]);
        tile[r][c * 4 + 0] = v.x; tile[r][c * 4 + 1] = v.y;
        tile[r][c * 4 + 2] = v.z; tile[r][c * 4 + 3] = v.w;
    }
    __syncthreads();

    const int nn = t & 31;
    #pragma unroll
    for (int i = 0; i < 2; ++i) {
        const int kk = (t >> 5) * 2 + i;
        Wtg[(size_t)(nt * 32 + nn) * 64 + kt * 16 + kk] =
            pack_bf16x2_rn(tile[kk * 2][nn], tile[kk * 2 + 1][nn]);
    }
}

// ---------------------------------------------------------------------------
// MFMA bf16 GEMM (block-specialized: last blocks do the edge histogram).
// GEMM: 64 rows/block, 16 rows/wave. A prefetched to registers (8x float4),
// B in XOR-swizzled LDS (stride 64 dwords, kc ^ (nn&15)) -> <=2-way banks.
// Outputs: h (fp32), hbu (bf16 pairs: dword p*16+c = pack(col 32p+c, 32p+16+c)),
// s1/s2 row dots.
// ---------------------------------------------------------------------------
__global__ __launch_bounds__(256) void gemm_h_kernel(
    const float* __restrict__ x, const unsigned int* __restrict__ Wtg,
    const float* __restrict__ a, float* __restrict__ h,
    unsigned int* __restrict__ hbu,
    float* __restrict__ s1, float* __restrict__ s2, int n,
    const int* __restrict__ ei, int* __restrict__ hist, int E, int gemm_blocks)
{
    __shared__ unsigned int Wtu[128 * 64];   // 32 KB exactly

    const int t = threadIdx.x;

    if (blockIdx.x >= gemm_blocks) {
        // ---- histogram-only blocks (no LDS, no barrier) ----
        const int E4   = E >> 2;
        const int nthr = (gridDim.x - gemm_blocks) << 8;
        const int g    = (blockIdx.x - gemm_blocks) * 256 + t;
        for (int idx = g; idx < E4; idx += nthr) {
            const int4 s4 = ((const int4*)ei)[idx];
            atomicAdd(&hist[s4.x], 1);
            atomicAdd(&hist[s4.y], 1);
            atomicAdd(&hist[s4.z], 1);
            atomicAdd(&hist[s4.w], 1);
        }
        for (int j = (E4 << 2) + g; j < E; j += nthr) atomicAdd(&hist[ei[j]], 1);
        return;
    }

    // ---- stage Wt with XOR swizzle: uint4 kc of row nn -> slot kc^(nn&15) ----
    #pragma unroll
    for (int i = 0; i < 8; ++i) {
        const int u  = i * 256 + t;
        const uint4 v = ((const uint4*)Wtg)[u];
        const int nn = u >> 4, kc = u & 15;
        *((uint4*)&Wtu[nn * 64 + (kc ^ (nn & 15)) * 4]) = v;
    }

    const int w    = t >> 6;
    const int lane = t & 63;
    const int c    = lane & 15;
    const int quad = lane >> 4;

    const int rowbase = blockIdx.x * 64 + w * 16;

    // ---- prefetch full x slice for this thread (one latency exposure) ----
    int arow = rowbase + c; if (arow >= n) arow = n - 1;
    const float4* xp = (const float4*)(x + (size_t)arow * NFEAT);
    float4 xv[8];
    #pragma unroll
    for (int s = 0; s < 4; ++s) {
        xv[2 * s]     = xp[s * 8 + quad * 2];
        xv[2 * s + 1] = xp[s * 8 + quad * 2 + 1];
    }

    float a1v[8], a2v[8];
    #pragma unroll
    for (int tt = 0; tt < 8; ++tt) {
        a1v[tt] = a[tt * 16 + c];
        a2v[tt] = a[NHID + tt * 16 + c];
    }

    f32x4 acc[8];
    #pragma unroll
    for (int tt = 0; tt < 8; ++tt) acc[tt] = (f32x4){0.f, 0.f, 0.f, 0.f};

    __syncthreads();

    #pragma unroll
    for (int s = 0; s < 4; ++s) {
        Frag afr;
        afr.u[0] = pack_bf16x2_rn(xv[2 * s].x,     xv[2 * s].y);
        afr.u[1] = pack_bf16x2_rn(xv[2 * s].z,     xv[2 * s].w);
        afr.u[2] = pack_bf16x2_rn(xv[2 * s + 1].x, xv[2 * s + 1].y);
        afr.u[3] = pack_bf16x2_rn(xv[2 * s + 1].z, xv[2 * s + 1].w);
        const int kc = s * 4 + quad;
        #pragma unroll
        for (int tt = 0; tt < 8; ++tt) {
            Frag bfr;
            bfr.v = *((const uint4*)&Wtu[(tt * 16 + c) * 64 + (kc ^ c) * 4]);
            acc[tt] = __builtin_amdgcn_mfma_f32_16x16x32_bf16(
                afr.s, bfr.s, acc[tt], 0, 0, 0);
        }
    }

    // ---- epilogue ----
    #pragma unroll
    for (int r = 0; r < 4; ++r) {
        const int  row = rowbase + quad * 4 + r;
        const bool ok  = (row < n);
        float p1 = 0.f, p2 = 0.f;
        #pragma unroll
        for (int tt = 0; tt < 8; ++tt) {
            const float v = acc[tt][r];
            if (ok) h[(size_t)row * NHID + tt * 16 + c] = v;
            p1 = fmaf(v, a1v[tt], p1);
            p2 = fmaf(v, a2v[tt], p2);
        }
        #pragma unroll
        for (int p = 0; p < 4; ++p) {
            if (ok) hbu[(size_t)row * 64 + p * 16 + c] =
                pack_bf16x2_rn(acc[2 * p][r], acc[2 * p + 1][r]);
        }
        #pragma unroll
        for (int off = 1; off <= 8; off <<= 1) {
            p1 += __shfl_xor(p1, off, 64);
            p2 += __shfl_xor(p2, off, 64);
        }
        if (ok && c == 0) { s1[row] = p1; s2[row] = p2; }
    }
}

__global__ __launch_bounds__(256) void scan_block_kernel(
    const int* __restrict__ in, int* __restrict__ out, int* __restrict__ bsums, int n)
{
    __shared__ int s[256];
    const int tid = threadIdx.x;
    const int gid = blockIdx.x * 256 + tid;
    const int v = (gid < n) ? in[gid] : 0;
    s[tid] = v;
    __syncthreads();
    #pragma unroll
    for (int off = 1; off < 256; off <<= 1) {
        const int t2 = (tid >= off) ? s[tid - off] : 0;
        __syncthreads();
        s[tid] += t2;
        __syncthreads();
    }
    if (gid < n) out[gid] = s[tid] - v;
    if (tid == 255 && bsums) bsums[blockIdx.x] = s[255];
}

__global__ __launch_bounds__(256) void scan_add_kernel(
    int* __restrict__ row_ptr, int* __restrict__ cursor,
    const int* __restrict__ bsums_scan, int n, int E)
{
    const int gid = blockIdx.x * 256 + threadIdx.x;
    if (gid < n) {
        const int v = row_ptr[gid] + bsums_scan[gid >> 8];
        row_ptr[gid] = v;
        cursor[gid]  = v;
    }
    if (gid == 0) row_ptr[n] = E;
}

// ---------------------------------------------------------------------------
// Scatter: 1 edge/thread, 4-byte records (dst<<16 | fp16(ev)).
// ---------------------------------------------------------------------------
__global__ __launch_bounds__(256) void scatter_kernel(
    const int* __restrict__ ei, const float* __restrict__ s1,
    const float* __restrict__ s2, int* __restrict__ cursor,
    unsigned int* __restrict__ erec, int E)
{
    const int j = blockIdx.x * 256 + threadIdx.x;
    if (j >= E) return;
    const int src = ei[j];
    const int dst = ei[E + j];
    float s = s1[src] + s2[dst];
    s = (s > 0.f) ? s : ALPHA * s;
    const float ev = expf(-s);
    const unsigned int evh = (unsigned int)__half_as_ushort(__float2half(ev));
    const int pos = atomicAdd(&cursor[src], 1);
    erec[pos] = ((unsigned int)dst << 16) | evh;
}

// ---------------------------------------------------------------------------
// Aggregate + finalize: 16-lane group per node (4 nodes/wave), 8-deep unroll.
// ---------------------------------------------------------------------------
__global__ __launch_bounds__(256) void aggregate_kernel(
    const int* __restrict__ row_ptr, const unsigned int* __restrict__ erec,
    const unsigned int* __restrict__ hbu, const float* __restrict__ h,
    float* __restrict__ out, int n)
{
    const int node = blockIdx.x * 16 + (threadIdx.x >> 4);
    const int l    = threadIdx.x & 15;
    if (node >= n) return;

    const int beg = row_ptr[node];
    const int end = row_ptr[node + 1];

    float acc[8];
    #pragma unroll
    for (int i = 0; i < 8; ++i) acc[i] = 0.f;
    float rs = 0.f;

    #define BL(x) __uint_as_float((x) << 16)
    #define BH(x) __uint_as_float((x) & 0xffff0000u)
    #define ACC4(u, ev)                                   \
        acc[0] = fmaf(ev, BL(u.x), acc[0]);               \
        acc[4] = fmaf(ev, BH(u.x), acc[4]);               \
        acc[1] = fmaf(ev, BL(u.y), acc[1]);               \
        acc[5] = fmaf(ev, BH(u.y), acc[5]);               \
        acc[2] = fmaf(ev, BL(u.z), acc[2]);               \
        acc[6] = fmaf(ev, BH(u.z), acc[6]);               \
        acc[3] = fmaf(ev, BL(u.w), acc[3]);               \
        acc[7] = fmaf(ev, BH(u.w), acc[7]);

    int e = beg;
    for (; e + 8 <= end; e += 8) {
        unsigned int rr[8];
        uint4 u[8];
        #pragma unroll
        for (int i = 0; i < 8; ++i) rr[i] = erec[e + i];
        #pragma unroll
        for (int i = 0; i < 8; ++i)
            u[i] = ((const uint4*)(hbu + (size_t)(rr[i] >> 16) * 64))[l];
        #pragma unroll
        for (int i = 0; i < 8; ++i) {
            const float ev = __half2float(__ushort_as_half((unsigned short)(rr[i] & 0xffffu)));
            ACC4(u[i], ev);
            rs += ev;
        }
    }
    for (; e + 2 <= end; e += 2) {
        const unsigned int r0 = erec[e], r1 = erec[e + 1];
        const uint4 u0 = ((const uint4*)(hbu + (size_t)(r0 >> 16) * 64))[l];
        const uint4 u1 = ((const uint4*)(hbu + (size_t)(r1 >> 16) * 64))[l];
        const float e0 = __half2float(__ushort_as_half((unsigned short)(r0 & 0xffffu)));
        const float e1 = __half2float(__ushort_as_half((unsigned short)(r1 & 0xffffu)));
        ACC4(u0, e0); ACC4(u1, e1);
        rs += e0 + e1;
    }
    if (e < end) {
        const unsigned int r0 = erec[e];
        const uint4 u0 = ((const uint4*)(hbu + (size_t)(r0 >> 16) * 64))[l];
        const float e0 = __half2float(__ushort_as_half((unsigned short)(r0 & 0xffffu)));
        ACC4(u0, e0);
        rs += e0;
    }
    #undef ACC4
    #undef BL
    #undef BH

    const float rinv = 1.0f / (rs + 1e-16f);
    const int p = l >> 2, q = l & 3;
    const float4* hp4 = (const float4*)(h + (size_t)node * NHID);
    const float4 ha = hp4[8 * p + q];
    const float4 hb = hp4[8 * p + 4 + q];
    float4 oa, ob;
    float z;
    z = ha.x - acc[0] * rinv; oa.x = (z > 0.f) ? z : (expf(z) - 1.f);
    z = ha.y - acc[1] * rinv; oa.y = (z > 0.f) ? z : (expf(z) - 1.f);
    z = ha.z - acc[2] * rinv; oa.z = (z > 0.f) ? z : (expf(z) - 1.f);
    z = ha.w - acc[3] * rinv; oa.w = (z > 0.f) ? z : (expf(z) - 1.f);
    z = hb.x - acc[4] * rinv; ob.x = (z > 0.f) ? z : (expf(z) - 1.f);
    z = hb.y - acc[5] * rinv; ob.y = (z > 0.f) ? z : (expf(z) - 1.f);
    z = hb.z - acc[6] * rinv; ob.z = (z > 0.f) ? z : (expf(z) - 1.f);
    z = hb.w - acc[7] * rinv; ob.w = (z > 0.f) ? z : (expf(z) - 1.f);
    float4* op = (float4*)(out + (size_t)node * NHID);
    op[8 * p + q]     = oa;
    op[8 * p + 4 + q] = ob;
}

// ---------------------------------------------------------------------------
extern "C" void kernel_launch(void* const* d_in, const int* in_sizes, int n_in,
                              void* d_out, int out_size, void* d_ws, size_t ws_size,
                              hipStream_t stream) {
    const float* x  = (const float*)d_in[0];
    const float* W  = (const float*)d_in[1];
    const float* a  = (const float*)d_in[2];
    const int*   ei = (const int*)d_in[3];

    const int n = in_sizes[0] / NFEAT;   // 50000
    const int E = in_sizes[3] / 2;       // 640000
    const int nb = (n + 255) / 256;

    float* out = (float*)d_out;

    // Workspace (4-byte units):
    //   h[n*128] | hbu[n*64] | s1[n] | s2[n] | erec[E] | Wtg[8192] |
    //   hist[n] | bsums[256] | bsums_scan[256] | row_ptr[n+1] | cursor[n]
    float*        h     = (float*)d_ws;
    unsigned int* hbu   = (unsigned int*)(h + (size_t)n * NHID);
    float*        s1    = (float*)(hbu + (size_t)n * 64);
    float*        s2    = s1 + n;
    unsigned int* erec  = (unsigned int*)(s2 + n);
    unsigned int* Wtg   = erec + E;
    int*          hist  = (int*)(Wtg + 8192);
    int*          bsums = hist + n;
    int*          bsums_scan = bsums + 256;
    int*          row_ptr    = bsums_scan + 256;
    int*          cursor     = row_ptr + (n + 1);

    hipMemsetAsync(hist, 0, ((size_t)n + 256) * sizeof(int), stream);

    prep_wt_kernel<<<16, 256, 0, stream>>>(W, Wtg);

    const int gemm_blocks = (n + 63) / 64;       // 782
    const int hist_blocks = 128;
    gemm_h_kernel<<<gemm_blocks + hist_blocks, 256, 0, stream>>>(
        x, Wtg, a, h, hbu, s1, s2, n, ei, hist, E, gemm_blocks);

    scan_block_kernel<<<nb, 256, 0, stream>>>(hist, row_ptr, bsums, n);
    scan_block_kernel<<<1, 256, 0, stream>>>(bsums, bsums_scan, nullptr, 256);
    scan_add_kernel<<<nb, 256, 0, stream>>>(row_ptr, cursor, bsums_scan, n, E);

    scatter_kernel<<<(E + 255) / 256, 256, 0, stream>>>(ei, s1, s2, cursor, erec, E);

    aggregate_kernel<<<(n + 15) / 16, 256, 0, stream>>>(row_ptr, erec, hbu, h, out, n);
}